// Round 8
// baseline (729.054 us; speedup 1.0000x reference)
//
#include <hip/hip_runtime.h>
#include <hip/hip_fp16.h>
#include <math.h>

#define N_NODES 50000
#define N_EDGES 800000
#define N_TOT   850000   // E + N self-loops
#define EPS_BN  1e-5f
#define GAT_SLOPE 0.2f
#define ACT_SLOPE 0.01f
#define NBUCK   ((N_NODES + 255) / 256)   // 196 dst-buckets (256 dsts each)
#define BCAP    5120                       // slots per bucket (mean 4337)
#define K1_CH   4096                       // edges per bucket_append block
#define K1_NB   ((N_TOT + K1_CH - 1) / K1_CH)   // 208
#define GB64    ((N_NODES + 63) / 64)      // 782 GEMM row-blocks

typedef _Float16 half8_t __attribute__((ext_vector_type(8)));
typedef _Float16 half4_t __attribute__((ext_vector_type(4)));
typedef _Float16 half2_t __attribute__((ext_vector_type(2)));
typedef float    f32x4   __attribute__((ext_vector_type(4)));

__device__ __forceinline__ float wred_max(float x) {
#pragma unroll
    for (int m = 32; m; m >>= 1) x = fmaxf(x, __shfl_xor(x, m, 64));
    return x;
}
__device__ __forceinline__ float wred_sum(float x) {
#pragma unroll
    for (int m = 32; m; m >>= 1) x += __shfl_xor(x, m, 64);
    return x;
}
__device__ __forceinline__ int wred_sum_i(int x) {
#pragma unroll
    for (int m = 32; m; m >>= 1) x += __shfl_xor(x, m, 64);
    return x;
}

// pack/unpack (sum, sumsq) into 8B for agent-scope atomic pbn traffic
__device__ __forceinline__ unsigned long long sq_pack(float s, float q) {
    return ((unsigned long long)__float_as_uint(q) << 32) | __float_as_uint(s);
}
__device__ __forceinline__ void sq_unpack(unsigned long long u, float& s, float& q) {
    s = __uint_as_float((unsigned)u);
    q = __uint_as_float((unsigned)(u >> 32));
}

// fragment-major weight permutation: wtF[cb][ks][tt][lane][8] so a wave's
// B-fragment load (fixed cb,ks,tt; lane varies) is ONE contiguous 1KB read.
__device__ __forceinline__ void wf_perm(const float* __restrict__ W,
                                        _Float16* __restrict__ wt,
                                        int K, int C, int i) {
    int j   = i & 7;          // half within lane's 16B
    int l   = (i >> 3) & 63;  // lane
    int rest = i >> 9;        // (cb*KS + ks)*4 + tt
    int tt  = rest & 3;
    int ksf = rest >> 2;
    int KS  = K >> 5;
    int cb  = ksf / KS, ks = ksf - cb * KS;
    int k   = ks * 32 + (l >> 4) * 8 + j;
    int c   = cb * 64 + tt * 16 + (l & 15);
    wt[i] = (_Float16)W[k * C + c];
}

// ---- one-shot init: W fragment-major fp16, a-vec matvecs, counters zero ----
__global__ void init_misc(const float* __restrict__ W1, const float* __restrict__ W2,
                          const float* __restrict__ Wf, _Float16* __restrict__ wt1,
                          _Float16* __restrict__ wt2, _Float16* __restrict__ wtf,
                          int* __restrict__ bcnt, int* __restrict__ gcnt,
                          const float* __restrict__ as1, const float* __restrict__ ad1,
                          const float* __restrict__ as2, const float* __restrict__ ad2,
                          float* __restrict__ va1, float* __restrict__ vb1,
                          float* __restrict__ va2, float* __restrict__ vb2) {
    int i = blockIdx.x * 256 + threadIdx.x;
    if (i < NBUCK) bcnt[i] = 0;
    if (i < 2) gcnt[i] = 0;            // last-block done-counters (per STATS GEMM)
    if (i < 8192) {                                  // W1: 64x128
        wf_perm(W1, wt1, 64, 128, i);
    } else if (i < 8192 + 32768) {                   // W2: 128x256
        wf_perm(W2, wt2, 128, 256, i - 8192);
    } else if (i < 8192 + 32768 + 65536) {           // Wf: 256x256
        wf_perm(Wf, wtf, 256, 256, i - 40960);
    } else if (i < 106496 + 384) {                   // a-vector matvecs
        int j = i - 106496;
        if (j < 64) {
            float s = 0.f;
            for (int c = 0; c < 128; ++c) s += W1[j * 128 + c] * as1[c];
            va1[j] = s;
        } else if (j < 128) {
            int k = j - 64; float s = 0.f;
            for (int c = 0; c < 128; ++c) s += W1[k * 128 + c] * ad1[c];
            vb1[k] = s;
        } else if (j < 256) {
            int k = j - 128; float s = 0.f;
            for (int c = 0; c < 256; ++c) s += W2[k * 256 + c] * as2[c];
            va2[k] = s;
        } else {
            int k = j - 256; float s = 0.f;
            for (int c = 0; c < 256; ++c) s += W2[k * 256 + c] * ad2[c];
            vb2[k] = s;
        }
    }
}

// ---- fused: bucketed-CSR pass 1 (blocks [0,K1_NB)) ∥ emb cast+dots (rest) ----
// Append part is single-pass: edges read once into registers (static unroll),
// LDS histogram, one global atomic per (block,bucket), run-local append.
__global__ __launch_bounds__(256) void
append_emb(const int* __restrict__ ei, int* __restrict__ bcnt,
           unsigned* __restrict__ bedge,
           const float* __restrict__ emb, const float* __restrict__ va,
           const float* __restrict__ vb, _Float16* __restrict__ embh,
           float* __restrict__ e_n, float* __restrict__ f_n) {
    const int t = threadIdx.x;
    if ((int)blockIdx.x < K1_NB) {
        __shared__ int lcnt[NBUCK], lrank[NBUCK], gbase[NBUCK];
        const int base = blockIdx.x * K1_CH;
        const int nE = min(K1_CH, N_TOT - base);
        for (int i = t; i < NBUCK; i += 256) { lcnt[i] = 0; lrank[i] = 0; }
        __syncthreads();
        unsigned r[16];
#pragma unroll
        for (int j = 0; j < 16; ++j) {
            int i = t + j * 256;
            if (i < nE) {
                int e = base + i;
                int s, d;
                if (e < N_EDGES) { s = ei[e]; d = ei[N_EDGES + e]; }
                else { s = e - N_EDGES; d = s; }
                r[j] = ((unsigned)d << 16) | (unsigned)s;
                atomicAdd(&lcnt[d >> 8], 1);
            }
        }
        __syncthreads();
        if (t < NBUCK && lcnt[t] > 0) gbase[t] = atomicAdd(&bcnt[t], lcnt[t]);
        __syncthreads();
#pragma unroll
        for (int j = 0; j < 16; ++j) {
            int i = t + j * 256;
            if (i < nE) {
                unsigned v = r[j];
                int bk = v >> 24;                       // d>>8 (d < 65536)
                int gp = gbase[bk] + atomicAdd(&lrank[bk], 1);
                if (gp < BCAP) bedge[(size_t)bk * BCAP + gp] = v;
            }
        }
        return;
    }
    int rr = ((int)blockIdx.x - K1_NB) * 4 + (t >> 6);
    if (rr >= N_NODES) return;
    int l = t & 63;
    float v = emb[(size_t)rr * 64 + l];
    embh[(size_t)rr * 64 + l] = (_Float16)v;
    float pe = wred_sum(v * va[l]);
    float pf = wred_sum(v * vb[l]);
    if (l == 0) { e_n[rr] = pe; f_n[rr] = pf; }
}

// ---- bucketed CSR pass 2: per-bucket local CSR in LDS ----
__global__ __launch_bounds__(256) void
bucket_csr(const int* __restrict__ bcnt, const unsigned* __restrict__ bedge,
           int* __restrict__ ptr, int* __restrict__ srcs) {
    __shared__ int lcnt[256], lptr[256], lrank[256];
    __shared__ int wsum[4];
    __shared__ int sbase;
    const int b = blockIdx.x, t = threadIdx.x;
    lcnt[t] = 0; lrank[t] = 0;
    if (t < 64) {                       // exclusive prefix over buckets < b
        int s = 0;
        for (int j = t; j < b; j += 64) s += bcnt[j];
        s = wred_sum_i(s);
        if (t == 0) sbase = s;
    }
    __syncthreads();
    const int cnt = min(bcnt[b], BCAP);
    const int base0 = sbase;
    const unsigned* eb = bedge + (size_t)b * BCAP;
    for (int i = t; i < cnt; i += 256) atomicAdd(&lcnt[(eb[i] >> 16) & 255], 1);
    __syncthreads();
    int lane = t & 63, w = t >> 6;
    int v = lcnt[t];
    int x = v;
#pragma unroll
    for (int off = 1; off < 64; off <<= 1) {
        int y = __shfl_up(x, off, 64);
        if (lane >= off) x += y;
    }
    if (lane == 63) wsum[w] = x;
    __syncthreads();
    if (t == 0) {
        int s = 0;
#pragma unroll
        for (int i = 0; i < 4; ++i) { int tmp = wsum[i]; wsum[i] = s; s += tmp; }
    }
    __syncthreads();
    lptr[t] = x - v + wsum[w];
    __syncthreads();
    int d = b * 256 + t;
    if (d < N_NODES) ptr[d] = base0 + lptr[t];
    if (b == NBUCK - 1 && t == 0) ptr[N_NODES] = base0 + cnt;
    for (int i = t; i < cnt; i += 256) {
        unsigned v2 = eb[i];
        int dl = (v2 >> 16) & 255;
        int pos = base0 + lptr[dl] + atomicAdd(&lrank[dl], 1);
        srcs[pos] = (int)(v2 & 0xFFFFu);
    }
}

// ---- layer-2: z = lrelu(bn(out1)) stored once (fp16) + logit dots ----
__global__ __launch_bounds__(256) void
ef_dots(const _Float16* __restrict__ x, const float* __restrict__ sc,
        const float* __restrict__ sh, const float* __restrict__ va,
        const float* __restrict__ vb, _Float16* __restrict__ z,
        float* __restrict__ e_n, float* __restrict__ f_n) {
    int r = blockIdx.x * 4 + (threadIdx.x >> 6);
    if (r >= N_NODES) return;
    int l = threadIdx.x & 63;
    int c = 2 * l;
    half2_t hv = *(const half2_t*)&x[(size_t)r * 128 + c];
    float x0 = (float)hv[0] * sc[c] + sh[c];
    float x1 = (float)hv[1] * sc[c + 1] + sh[c + 1];
    x0 = x0 > 0.f ? x0 : ACT_SLOPE * x0;
    x1 = x1 > 0.f ? x1 : ACT_SLOPE * x1;
    half2_t zo = { (_Float16)x0, (_Float16)x1 };
    *(half2_t*)&z[(size_t)r * 128 + c] = zo;
    float pe = wred_sum(x0 * va[c] + x1 * va[c + 1]);
    float pf = wred_sum(x0 * vb[c] + x1 * vb[c + 1]);
    if (l == 0) { e_n[r] = pe; f_n[r] = pf; }
}

// ---- MFMA GEMM: out[n x C] = act(bn(x))[n x K] @ W[K x C] (+bias) ----
// 256 thr = 4 waves; 64 rows x CB cols per block; grid = rowblks x (C/CB).
// B from fragment-major wt (coalesced 1KB wave-loads), register dbuf.
// Epilogue: acc -> fp32 LDS cbuf (unioned with staging xs) -> coalesced
// float4/half4 row-major stores. If STATS: per-block column sum/sumsq
// published via AGENT-scope atomic stores (cross-XCD-visible), then a
// done-counter; the LAST block reduces all partials -> scale/shift in-kernel
// (replaces the separate bn_coef dispatch).
template<int K, int C, int CB, typename InT, typename OutT, bool STATS>
__global__ __launch_bounds__(256) void
gemm_mfma(const InT* __restrict__ x, const _Float16* __restrict__ wt,
          const float* __restrict__ bias, OutT* __restrict__ out, int n,
          const float* __restrict__ scale, const float* __restrict__ shift,
          float2* __restrict__ pbn,
          const float* __restrict__ gamma, const float* __restrict__ beta,
          float* __restrict__ o_scale, float* __restrict__ o_shift,
          int* __restrict__ done) {
    constexpr int NW_C = CB / 64;      // col groups per block (1 or 2)
    constexpr int RT   = NW_C;         // row tiles per wave (rows/wave = 16*NW_C)
    constexpr int NCB  = C / CB;       // col blocks
    constexpr int KS   = K / 32;       // k-steps
    constexpr int LK   = K + 8;        // staging row stride (halves)
    constexpr int LCB  = CB + 4;       // cbuf row stride (floats, 16B-aligned)
    constexpr size_t SMB = ((size_t)64 * LK * 2 > (size_t)64 * LCB * 4)
                             ? (size_t)64 * LK * 2 : (size_t)64 * LCB * 4;
    __shared__ alignas(16) char smem[SMB];
    _Float16* xs  = (_Float16*)smem;
    float*   cbuf = (float*)smem;
    __shared__ float cs_sh[STATS ? CB : 1];
    __shared__ float cq_sh[STATS ? CB : 1];

    const int rb = blockIdx.x / NCB;
    const int cblk = blockIdx.x - rb * NCB;
    const int row0 = rb * 64;
    const int colB = cblk * CB;
    const int t = threadIdx.x;

    if (STATS) {
        for (int c = t; c < CB; c += 256) { cs_sh[c] = 0.f; cq_sh[c] = 0.f; }
    }

    // ---- stage x rows (optionally BN+lrelu fused) into LDS fp16 ----
    if constexpr (__is_same(InT, _Float16)) {
        for (int i = t * 8; i < 64 * K; i += 256 * 8) {
            int r = i / K, c = i - (i / K) * K;
            half8_t v = {};
            if (row0 + r < n) v = *(const half8_t*)&x[(size_t)(row0 + r) * K + c];
            if (scale) {
#pragma unroll
                for (int j = 0; j < 8; ++j) {
                    float f = (float)v[j] * scale[c + j] + shift[c + j];
                    v[j] = (_Float16)(f > 0.f ? f : ACT_SLOPE * f);
                }
            }
            *(half8_t*)&xs[r * LK + c] = v;
        }
    } else {
        for (int i = t * 4; i < 64 * K; i += 256 * 4) {
            int r = i / K, c = i - (i / K) * K;
            float4 v = make_float4(0.f, 0.f, 0.f, 0.f);
            if (row0 + r < n) v = *(const float4*)&x[(size_t)(row0 + r) * K + c];
            if (scale) {
                v.x = v.x * scale[c] + shift[c];         v.x = v.x > 0.f ? v.x : ACT_SLOPE * v.x;
                v.y = v.y * scale[c + 1] + shift[c + 1]; v.y = v.y > 0.f ? v.y : ACT_SLOPE * v.y;
                v.z = v.z * scale[c + 2] + shift[c + 2]; v.z = v.z > 0.f ? v.z : ACT_SLOPE * v.z;
                v.w = v.w * scale[c + 3] + shift[c + 3]; v.w = v.w > 0.f ? v.w : ACT_SLOPE * v.w;
            }
            half4_t h4 = { (_Float16)v.x, (_Float16)v.y, (_Float16)v.z, (_Float16)v.w };
            *(half4_t*)&xs[r * LK + c] = h4;
        }
    }
    __syncthreads();

    const int w = t >> 6, l = t & 63;
    const int l16 = l & 15, quad = l >> 4;
    const int lc0 = (w % NW_C) * 64;          // block-local col base of this wave
    const int gc0 = colB + lc0;               // global col base
    const int mbase = (w / NW_C) * (16 * NW_C);
    // fragment-major base for this wave's col-block, lane-contiguous
    const _Float16* wtw = wt + (size_t)(gc0 >> 6) * KS * 4 * 512 + l * 8;

    f32x4 acc[RT][4] = {};
    half8_t bA[4], bB[4];
    auto loadB = [&](int k0, half8_t* bf) {
        const _Float16* p = wtw + (size_t)(k0 >> 5) * 4 * 512;
#pragma unroll
        for (int tt = 0; tt < 4; ++tt)
            bf[tt] = *(const half8_t*)&p[tt * 512];
    };
    auto doMM = [&](int k0, half8_t* bf) {
        half8_t a[RT];
#pragma unroll
        for (int rt = 0; rt < RT; ++rt)
            a[rt] = *(const half8_t*)&xs[(mbase + rt * 16 + l16) * LK + k0 + quad * 8];
#pragma unroll
        for (int rt = 0; rt < RT; ++rt)
#pragma unroll
            for (int tt = 0; tt < 4; ++tt)
                acc[rt][tt] = __builtin_amdgcn_mfma_f32_16x16x32_f16(a[rt], bf[tt],
                                                                     acc[rt][tt], 0, 0, 0);
    };
    loadB(0, bA);
#pragma unroll
    for (int k0 = 0; k0 < K; k0 += 64) {
        loadB(k0 + 32, bB);
        doMM(k0, bA);
        if (k0 + 64 < K) loadB(k0 + 64, bA);
        doMM(k0 + 32, bB);
    }

    // ---- epilogue: acc -> cbuf (+bias), stats from registers ----
    __syncthreads();   // xs dead (a-frags consumed), cbuf takes over smem
#pragma unroll
    for (int rt = 0; rt < RT; ++rt) {
#pragma unroll
        for (int tt = 0; tt < 4; ++tt) {
            int lcol = lc0 + tt * 16 + l16;
            float bb = bias ? bias[colB + lcol] : 0.f;
            float s = 0.f, q = 0.f;
#pragma unroll
            for (int i = 0; i < 4; ++i) {
                int lrow = mbase + rt * 16 + quad * 4 + i;
                float v = acc[rt][tt][i] + bb;
                cbuf[lrow * LCB + lcol] = v;
                if (STATS && row0 + lrow < n) { s += v; q += v * v; }
            }
            if constexpr (STATS) {
                s += __shfl_xor(s, 16, 64); s += __shfl_xor(s, 32, 64);
                q += __shfl_xor(q, 16, 64); q += __shfl_xor(q, 32, 64);
                if (quad == 0) {
                    atomicAdd(&cs_sh[lcol], s);
                    atomicAdd(&cq_sh[lcol], q);
                }
            }
        }
    }
    __syncthreads();
    if constexpr (STATS) {
        // agent-scope publish: visible across XCDs for the last-block reducer
        for (int c = t; c < CB; c += 256)
            __hip_atomic_store(
                (unsigned long long*)&pbn[(size_t)rb * C + colB + c],
                sq_pack(cs_sh[c], cq_sh[c]),
                __ATOMIC_RELAXED, __HIP_MEMORY_SCOPE_AGENT);
    }
    // ---- coalesced row-major store ----
    for (int i = t * 4; i < 64 * CB; i += 256 * 4) {
        int r = i / CB, c = i - (i / CB) * CB;
        if (row0 + r < n) {
            float4 v4 = *(const float4*)&cbuf[r * LCB + c];
            if constexpr (__is_same(OutT, float)) {
                *(float4*)&out[(size_t)(row0 + r) * C + colB + c] = v4;
            } else {
                half4_t h4 = { (_Float16)v4.x, (_Float16)v4.y,
                               (_Float16)v4.z, (_Float16)v4.w };
                *(half4_t*)&out[(size_t)(row0 + r) * C + colB + c] = h4;
            }
        }
    }

    // ---- decoupled last-block bn_coef (replaces separate dispatch) ----
    if constexpr (STATS) {
        __shared__ bool isLast;
        __syncthreads();   // barrier drains vmcnt -> this block's pbn stores done
        if (t == 0) {
            int old = __hip_atomic_fetch_add(done, 1, __ATOMIC_ACQ_REL,
                                             __HIP_MEMORY_SCOPE_AGENT);
            isLast = (old == (int)gridDim.x - 1);
        }
        __syncthreads();
        if (isLast) {
            const int PB = (int)gridDim.x / NCB;   // rowblocks
            for (int c = t; c < C; c += 256) {
                float s = 0.f, q = 0.f;
                for (int b = 0; b < PB; ++b) {
                    float ps, pq;
                    sq_unpack(__hip_atomic_load(
                                  (const unsigned long long*)&pbn[(size_t)b * C + c],
                                  __ATOMIC_RELAXED, __HIP_MEMORY_SCOPE_AGENT),
                              ps, pq);
                    s += ps; q += pq;
                }
                float mu  = s / N_NODES;
                float var = q / N_NODES - mu * mu;
                float scv = gamma[c] * rsqrtf(var + EPS_BN);
                o_scale[c] = scv;
                o_shift[c] = beta[c] - mu * scv;
            }
        }
    }
}

// ---- fused softmax + weighted gather over the GEMM *input* rows ----
template<int C>
__global__ __launch_bounds__(256) void
attn_aggregate(const _Float16* __restrict__ h, const int* __restrict__ srcs,
               const int* __restrict__ ptr, const float* __restrict__ e_n,
               const float* __restrict__ f_n, _Float16* __restrict__ out) {
    constexpr int RL = C / 8;          // lanes per row: 8 (C=64) or 16 (C=128)
    constexpr int G  = 64 / RL;        // row groups per wave: 8 or 4
    int d = blockIdx.x * 4 + (threadIdx.x >> 6);
    if (d >= N_NODES) return;
    int l  = threadIdx.x & 63;
    int b0 = ptr[d], b1 = ptr[d + 1];
    int deg = b1 - b0;
    float fd = f_n[d];
    const int g  = l / RL;
    const int cl = l % RL;
    float acc[8] = {0.f, 0.f, 0.f, 0.f, 0.f, 0.f, 0.f, 0.f};

    if (deg <= 64) {
        int sj = 0; float lg = -1e30f;
        if (l < deg) {
            sj = srcs[b0 + l];
            float v = e_n[sj] + fd;
            lg = v > 0.f ? v : GAT_SLOPE * v;
        }
        float m  = wred_max(lg);
        float e0 = (l < deg) ? __expf(lg - m) : 0.f;
        float ex = e0 / wred_sum(e0);

        int jj = 0;
        for (; jj + 4 * G <= deg; jj += 4 * G) {     // 4 loads in flight / group
            float wk[4]; int sk[4];
#pragma unroll
            for (int k = 0; k < 4; ++k) {
                int j = jj + k * G + g;
                wk[k] = __shfl(ex, j, 64);
                sk[k] = __shfl(sj, j, 64);
            }
            half8_t v[4];
#pragma unroll
            for (int k = 0; k < 4; ++k)
                v[k] = *(const half8_t*)&h[(size_t)sk[k] * C + cl * 8];
#pragma unroll
            for (int k = 0; k < 4; ++k)
#pragma unroll
                for (int i = 0; i < 8; ++i)
                    acc[i] += wk[k] * (float)v[k][i];
        }
        for (; jj + 2 * G <= deg; jj += 2 * G) {
            float w1 = __shfl(ex, jj + g, 64);
            int   s1 = __shfl(sj, jj + g, 64);
            float w2 = __shfl(ex, jj + G + g, 64);
            int   s2 = __shfl(sj, jj + G + g, 64);
            half8_t v1 = *(const half8_t*)&h[(size_t)s1 * C + cl * 8];
            half8_t v2 = *(const half8_t*)&h[(size_t)s2 * C + cl * 8];
#pragma unroll
            for (int i = 0; i < 8; ++i)
                acc[i] += w1 * (float)v1[i] + w2 * (float)v2[i];
        }
        for (; jj < deg; jj += G) {                  // exact tail
            int j = jj + g;
            float wk = __shfl(ex, j, 64);
            int   sk = __shfl(sj, j, 64);
            if (j < deg) {
                half8_t v = *(const half8_t*)&h[(size_t)sk * C + cl * 8];
#pragma unroll
                for (int i = 0; i < 8; ++i) acc[i] += wk * (float)v[i];
            }
        }
    } else {
        float m_l = -1e30f, den_l = 0.f;
        for (int j = b0 + l; j < b1; j += 64) {
            float lg = e_n[srcs[j]] + fd;
            lg = lg > 0.f ? lg : GAT_SLOPE * lg;
            float nm = fmaxf(m_l, lg);
            den_l = den_l * __expf(m_l - nm) + __expf(lg - nm);
            m_l = nm;
        }
        float m = wred_max(m_l);
        float inv = 1.f / wred_sum(den_l * __expf(m_l - m));
        for (int c0 = b0; c0 < b1; c0 += 64) {
            int jl = c0 + l;
            int sj = 0; float ex = 0.f;
            if (jl < b1) {
                sj = srcs[jl];
                float lg = e_n[sj] + fd;
                lg = lg > 0.f ? lg : GAT_SLOPE * lg;
                ex = __expf(lg - m) * inv;
            }
            int nE = min(64, b1 - c0);
            for (int jj = 0; jj < nE; jj += 2 * G) {
                int j1 = jj + g, j2 = jj + G + g;
                float w1 = __shfl(ex, j1, 64);
                int   s1 = __shfl(sj, j1, 64);
                float w2 = __shfl(ex, j2, 64);
                int   s2 = __shfl(sj, j2, 64);
                half8_t v1 = *(const half8_t*)&h[(size_t)s1 * C + cl * 8];
                half8_t v2 = *(const half8_t*)&h[(size_t)s2 * C + cl * 8];
#pragma unroll
                for (int i = 0; i < 8; ++i)
                    acc[i] += w1 * (float)v1[i] + w2 * (float)v2[i];
            }
        }
    }
#pragma unroll
    for (int mm = RL; mm < 64; mm <<= 1)
#pragma unroll
        for (int i = 0; i < 8; ++i) acc[i] += __shfl_xor(acc[i], mm, 64);
    if (g == 0) {
        int c = cl * 8;
        half8_t o;
#pragma unroll
        for (int i = 0; i < 8; ++i) o[i] = (_Float16)acc[i];
        *(half8_t*)&out[(size_t)d * C + c] = o;
    }
}

extern "C" void kernel_launch(void* const* d_in, const int* in_sizes, int n_in,
                              void* d_out, int out_size, void* d_ws, size_t ws_size,
                              hipStream_t stream) {
    const float* emb  = (const float*)d_in[0];
    const int*   ei   = (const int*)  d_in[1];
    const float* W1   = (const float*)d_in[2];
    const float* as1  = (const float*)d_in[3];
    const float* ad1  = (const float*)d_in[4];
    const float* b1   = (const float*)d_in[5];
    const float* g1   = (const float*)d_in[6];
    const float* be1  = (const float*)d_in[7];
    const float* W2   = (const float*)d_in[8];
    const float* as2  = (const float*)d_in[9];
    const float* ad2  = (const float*)d_in[10];
    const float* b2   = (const float*)d_in[11];
    const float* g2   = (const float*)d_in[12];
    const float* be2  = (const float*)d_in[13];
    const float* Wf   = (const float*)d_in[14];
    const float* bf   = (const float*)d_in[15];
    float* out = (float*)d_out;

    char* w = (char*)d_ws;
    auto alloc = [&](size_t bytes) {
        char* p = w;
        w += (bytes + 255) & ~(size_t)255;
        return (void*)p;
    };
    // embh and agg1 are contiguous (each 6.4MB, 256B-aligned) — together they
    // are reused as z1h (12.8MB) after both are dead.
    _Float16* embh = (_Float16*)alloc((size_t)N_NODES * 64 * 2);   // emb fp16
    _Float16* agg1 = (_Float16*)alloc((size_t)N_NODES * 64 * 2);   // layer-1 aggregate
    _Float16* out1 = (_Float16*)alloc((size_t)N_NODES * 128 * 2);  // agg1 @ W1 + b1
    _Float16* agg2 = (_Float16*)alloc((size_t)N_NODES * 128 * 2);  // layer-2 aggregate
    _Float16* out2 = (_Float16*)alloc((size_t)N_NODES * 256 * 2);  // agg2 @ W2 + b2
    _Float16* z1h  = embh;                       // alias: lrelu(bn(out1)), 12.8MB
    unsigned* bedge = (unsigned*)out2;           // alias: bucket edges (4MB), dead
                                                 // before out2 is written
    float*  e_n  = (float*) alloc((size_t)N_NODES * 4);
    float*  f_n  = (float*) alloc((size_t)N_NODES * 4);
    int*    srcs = (int*)   alloc((size_t)N_TOT * 4);
    int*    bcnt = (int*)   alloc((size_t)NBUCK * 4);
    int*    gcnt = (int*)   alloc(2 * 4);
    int*    ptr  = (int*)   alloc((size_t)(N_NODES + 1) * 4);
    float2* pbn  = (float2*)alloc((size_t)GB64 * 256 * 8);   // 1.6 MiB
    float*  sc1  = (float*) alloc(128 * 4);
    float*  sh1  = (float*) alloc(128 * 4);
    float*  sc2  = (float*) alloc(256 * 4);
    float*  sh2  = (float*) alloc(256 * 4);
    float*  va1  = (float*) alloc(64 * 4);
    float*  vb1  = (float*) alloc(64 * 4);
    float*  va2  = (float*) alloc(128 * 4);
    float*  vb2  = (float*) alloc(128 * 4);
    _Float16* wt1 = (_Float16*)alloc((size_t)64 * 128 * 2);
    _Float16* wt2 = (_Float16*)alloc((size_t)128 * 256 * 2);
    _Float16* wtf = (_Float16*)alloc((size_t)256 * 256 * 2);

    const int RW4 = (N_NODES + 3) / 4;   // wave-per-row grids

    // 1) init: weight fragment-major + a-vec matvecs + counter zero
    init_misc<<<(106496 + 384 + 255) / 256, 256, 0, stream>>>(
        W1, W2, Wf, wt1, wt2, wtf, bcnt, gcnt,
        as1, ad1, as2, ad2, va1, vb1, va2, vb2);

    // 2) fused: bucket append (single-pass) ∥ emb cast + layer-1 logits
    append_emb<<<K1_NB + RW4, 256, 0, stream>>>(
        ei, bcnt, bedge, emb, va1, vb1, embh, e_n, f_n);

    // 3) per-bucket CSR
    bucket_csr<<<NBUCK, 256, 0, stream>>>(bcnt, bedge, ptr, srcs);

    // 4) layer-1 aggregate (128B rows)
    attn_aggregate<64><<<RW4, 256, 0, stream>>>(embh, srcs, ptr, e_n, f_n, agg1);

    // 5) GEMM 64->128 + in-kernel BN1 stats/coef (last block)
    gemm_mfma<64, 128, 128, _Float16, _Float16, true><<<GB64, 256, 0, stream>>>(
        agg1, wt1, b1, out1, N_NODES, nullptr, nullptr, pbn, g1, be1, sc1, sh1, gcnt);

    // 6) z1 = lrelu(bn(out1)) stored once + layer-2 logits
    ef_dots<<<RW4, 256, 0, stream>>>(out1, sc1, sh1, va2, vb2, z1h, e_n, f_n);

    // 7) layer-2 aggregate (256B rows)
    attn_aggregate<128><<<RW4, 256, 0, stream>>>(z1h, srcs, ptr, e_n, f_n, agg2);

    // 8) GEMM 128->256 + in-kernel BN2 stats/coef (last block)
    gemm_mfma<128, 256, 128, _Float16, _Float16, true><<<GB64 * 2, 256, 0, stream>>>(
        agg2, wt2, b2, out2, N_NODES, nullptr, nullptr, pbn, g2, be2, sc2, sh2,
        gcnt + 1);

    // 9) final linear 256->256 (BN2+lrelu fused into staging)
    gemm_mfma<256, 256, 128, _Float16, float, false><<<GB64 * 2, 256, 0, stream>>>(
        out2, wtf, bf, out, N_NODES, sc2, sh2, nullptr,
        nullptr, nullptr, nullptr, nullptr, nullptr);
}

// Round 9
// 282.152 us; speedup vs baseline: 2.5839x; 2.5839x over previous
//
#include <hip/hip_runtime.h>
#include <hip/hip_fp16.h>
#include <math.h>

#define N_NODES 50000
#define N_EDGES 800000
#define N_TOT   850000   // E + N self-loops
#define EPS_BN  1e-5f
#define GAT_SLOPE 0.2f
#define ACT_SLOPE 0.01f
#define NBUCK   ((N_NODES + 255) / 256)   // 196 dst-buckets (256 dsts each)
#define BCAP    5120                       // slots per bucket (mean 4337)
#define K1_CH   4096                       // edges per bucket_append block
#define K1_NB   ((N_TOT + K1_CH - 1) / K1_CH)   // 208
#define GB64    ((N_NODES + 63) / 64)      // 782 GEMM row-blocks

typedef _Float16 half8_t __attribute__((ext_vector_type(8)));
typedef _Float16 half4_t __attribute__((ext_vector_type(4)));
typedef _Float16 half2_t __attribute__((ext_vector_type(2)));
typedef float    f32x4   __attribute__((ext_vector_type(4)));

__device__ __forceinline__ float wred_max(float x) {
#pragma unroll
    for (int m = 32; m; m >>= 1) x = fmaxf(x, __shfl_xor(x, m, 64));
    return x;
}
__device__ __forceinline__ float wred_sum(float x) {
#pragma unroll
    for (int m = 32; m; m >>= 1) x += __shfl_xor(x, m, 64);
    return x;
}
__device__ __forceinline__ int wred_sum_i(int x) {
#pragma unroll
    for (int m = 32; m; m >>= 1) x += __shfl_xor(x, m, 64);
    return x;
}

// fragment-major weight permutation: wtF[cb][ks][tt][lane][8] so a wave's
// B-fragment load (fixed cb,ks,tt; lane varies) is ONE contiguous 1KB read.
__device__ __forceinline__ void wf_perm(const float* __restrict__ W,
                                        _Float16* __restrict__ wt,
                                        int K, int C, int i) {
    int j   = i & 7;          // half within lane's 16B
    int l   = (i >> 3) & 63;  // lane
    int rest = i >> 9;        // (cb*KS + ks)*4 + tt
    int tt  = rest & 3;
    int ksf = rest >> 2;
    int KS  = K >> 5;
    int cb  = ksf / KS, ks = ksf - cb * KS;
    int k   = ks * 32 + (l >> 4) * 8 + j;
    int c   = cb * 64 + tt * 16 + (l & 15);
    wt[i] = (_Float16)W[k * C + c];
}

// ---- one-shot init: W fragment-major fp16, a-vec matvecs, bcnt zero ----
__global__ void init_misc(const float* __restrict__ W1, const float* __restrict__ W2,
                          const float* __restrict__ Wf, _Float16* __restrict__ wt1,
                          _Float16* __restrict__ wt2, _Float16* __restrict__ wtf,
                          int* __restrict__ bcnt,
                          const float* __restrict__ as1, const float* __restrict__ ad1,
                          const float* __restrict__ as2, const float* __restrict__ ad2,
                          float* __restrict__ va1, float* __restrict__ vb1,
                          float* __restrict__ va2, float* __restrict__ vb2) {
    int i = blockIdx.x * 256 + threadIdx.x;
    if (i < NBUCK) bcnt[i] = 0;
    if (i < 8192) {                                  // W1: 64x128
        wf_perm(W1, wt1, 64, 128, i);
    } else if (i < 8192 + 32768) {                   // W2: 128x256
        wf_perm(W2, wt2, 128, 256, i - 8192);
    } else if (i < 8192 + 32768 + 65536) {           // Wf: 256x256
        wf_perm(Wf, wtf, 256, 256, i - 40960);
    } else if (i < 106496 + 384) {                   // a-vector matvecs
        int j = i - 106496;
        if (j < 64) {
            float s = 0.f;
            for (int c = 0; c < 128; ++c) s += W1[j * 128 + c] * as1[c];
            va1[j] = s;
        } else if (j < 128) {
            int k = j - 64; float s = 0.f;
            for (int c = 0; c < 128; ++c) s += W1[k * 128 + c] * ad1[c];
            vb1[k] = s;
        } else if (j < 256) {
            int k = j - 128; float s = 0.f;
            for (int c = 0; c < 256; ++c) s += W2[k * 256 + c] * as2[c];
            va2[k] = s;
        } else {
            int k = j - 256; float s = 0.f;
            for (int c = 0; c < 256; ++c) s += W2[k * 256 + c] * ad2[c];
            vb2[k] = s;
        }
    }
}

// ---- fused: bucketed-CSR pass 1 (blocks [0,K1_NB)) ∥ emb cast+dots (rest) ----
// Append part is single-pass: edges read once into registers (static unroll),
// LDS histogram, one global atomic per (block,bucket), run-local append.
__global__ __launch_bounds__(256) void
append_emb(const int* __restrict__ ei, int* __restrict__ bcnt,
           unsigned* __restrict__ bedge,
           const float* __restrict__ emb, const float* __restrict__ va,
           const float* __restrict__ vb, _Float16* __restrict__ embh,
           float* __restrict__ e_n, float* __restrict__ f_n) {
    const int t = threadIdx.x;
    if ((int)blockIdx.x < K1_NB) {
        __shared__ int lcnt[NBUCK], lrank[NBUCK], gbase[NBUCK];
        const int base = blockIdx.x * K1_CH;
        const int nE = min(K1_CH, N_TOT - base);
        for (int i = t; i < NBUCK; i += 256) { lcnt[i] = 0; lrank[i] = 0; }
        __syncthreads();
        unsigned r[16];
#pragma unroll
        for (int j = 0; j < 16; ++j) {
            int i = t + j * 256;
            if (i < nE) {
                int e = base + i;
                int s, d;
                if (e < N_EDGES) { s = ei[e]; d = ei[N_EDGES + e]; }
                else { s = e - N_EDGES; d = s; }
                r[j] = ((unsigned)d << 16) | (unsigned)s;
                atomicAdd(&lcnt[d >> 8], 1);
            }
        }
        __syncthreads();
        if (t < NBUCK && lcnt[t] > 0) gbase[t] = atomicAdd(&bcnt[t], lcnt[t]);
        __syncthreads();
#pragma unroll
        for (int j = 0; j < 16; ++j) {
            int i = t + j * 256;
            if (i < nE) {
                unsigned v = r[j];
                int bk = v >> 24;                       // d>>8 (d < 65536)
                int gp = gbase[bk] + atomicAdd(&lrank[bk], 1);
                if (gp < BCAP) bedge[(size_t)bk * BCAP + gp] = v;
            }
        }
        return;
    }
    int rr = ((int)blockIdx.x - K1_NB) * 4 + (t >> 6);
    if (rr >= N_NODES) return;
    int l = t & 63;
    float v = emb[(size_t)rr * 64 + l];
    embh[(size_t)rr * 64 + l] = (_Float16)v;
    float pe = wred_sum(v * va[l]);
    float pf = wred_sum(v * vb[l]);
    if (l == 0) { e_n[rr] = pe; f_n[rr] = pf; }
}

// ---- bucketed CSR pass 2: per-bucket local CSR in LDS ----
__global__ __launch_bounds__(256) void
bucket_csr(const int* __restrict__ bcnt, const unsigned* __restrict__ bedge,
           int* __restrict__ ptr, int* __restrict__ srcs) {
    __shared__ int lcnt[256], lptr[256], lrank[256];
    __shared__ int wsum[4];
    __shared__ int sbase;
    const int b = blockIdx.x, t = threadIdx.x;
    lcnt[t] = 0; lrank[t] = 0;
    if (t < 64) {                       // exclusive prefix over buckets < b
        int s = 0;
        for (int j = t; j < b; j += 64) s += bcnt[j];
        s = wred_sum_i(s);
        if (t == 0) sbase = s;
    }
    __syncthreads();
    const int cnt = min(bcnt[b], BCAP);
    const int base0 = sbase;
    const unsigned* eb = bedge + (size_t)b * BCAP;
    for (int i = t; i < cnt; i += 256) atomicAdd(&lcnt[(eb[i] >> 16) & 255], 1);
    __syncthreads();
    int lane = t & 63, w = t >> 6;
    int v = lcnt[t];
    int x = v;
#pragma unroll
    for (int off = 1; off < 64; off <<= 1) {
        int y = __shfl_up(x, off, 64);
        if (lane >= off) x += y;
    }
    if (lane == 63) wsum[w] = x;
    __syncthreads();
    if (t == 0) {
        int s = 0;
#pragma unroll
        for (int i = 0; i < 4; ++i) { int tmp = wsum[i]; wsum[i] = s; s += tmp; }
    }
    __syncthreads();
    lptr[t] = x - v + wsum[w];
    __syncthreads();
    int d = b * 256 + t;
    if (d < N_NODES) ptr[d] = base0 + lptr[t];
    if (b == NBUCK - 1 && t == 0) ptr[N_NODES] = base0 + cnt;
    for (int i = t; i < cnt; i += 256) {
        unsigned v2 = eb[i];
        int dl = (v2 >> 16) & 255;
        int pos = base0 + lptr[dl] + atomicAdd(&lrank[dl], 1);
        srcs[pos] = (int)(v2 & 0xFFFFu);
    }
}

// ---- layer-2: z = lrelu(bn(out1)) stored once (fp16) + logit dots ----
__global__ __launch_bounds__(256) void
ef_dots(const _Float16* __restrict__ x, const float* __restrict__ sc,
        const float* __restrict__ sh, const float* __restrict__ va,
        const float* __restrict__ vb, _Float16* __restrict__ z,
        float* __restrict__ e_n, float* __restrict__ f_n) {
    int r = blockIdx.x * 4 + (threadIdx.x >> 6);
    if (r >= N_NODES) return;
    int l = threadIdx.x & 63;
    int c = 2 * l;
    half2_t hv = *(const half2_t*)&x[(size_t)r * 128 + c];
    float x0 = (float)hv[0] * sc[c] + sh[c];
    float x1 = (float)hv[1] * sc[c + 1] + sh[c + 1];
    x0 = x0 > 0.f ? x0 : ACT_SLOPE * x0;
    x1 = x1 > 0.f ? x1 : ACT_SLOPE * x1;
    half2_t zo = { (_Float16)x0, (_Float16)x1 };
    *(half2_t*)&z[(size_t)r * 128 + c] = zo;
    float pe = wred_sum(x0 * va[c] + x1 * va[c + 1]);
    float pf = wred_sum(x0 * vb[c] + x1 * vb[c + 1]);
    if (l == 0) { e_n[r] = pe; f_n[r] = pf; }
}

// ---- MFMA GEMM: out[n x C] = act(bn(x))[n x K] @ W[K x C] (+bias) ----
// 256 thr = 4 waves; 64 rows x CB cols per block; grid = rowblks x (C/CB).
// B from fragment-major wt (coalesced 1KB wave-loads), register dbuf.
// Epilogue: acc -> fp32 LDS cbuf (unioned with staging xs) -> coalesced
// float4/half4 row-major stores. If STATS: per-block column sum/sumsq via
// quad-shfl + LDS atomics -> pbn (plain stores; the separate bn_coef dispatch
// is the cross-XCD fence — in-kernel agent-scope fences cost an L2
// invalidate per block and serialized the whole GEMM in round 8).
template<int K, int C, int CB, typename InT, typename OutT, bool STATS>
__global__ __launch_bounds__(256) void
gemm_mfma(const InT* __restrict__ x, const _Float16* __restrict__ wt,
          const float* __restrict__ bias, OutT* __restrict__ out, int n,
          const float* __restrict__ scale, const float* __restrict__ shift,
          float2* __restrict__ pbn) {
    constexpr int NW_C = CB / 64;      // col groups per block (1 or 2)
    constexpr int RT   = NW_C;         // row tiles per wave (rows/wave = 16*NW_C)
    constexpr int NCB  = C / CB;       // col blocks
    constexpr int KS   = K / 32;       // k-steps
    constexpr int LK   = K + 8;        // staging row stride (halves)
    constexpr int LCB  = CB + 4;       // cbuf row stride (floats, 16B-aligned)
    constexpr size_t SMB = ((size_t)64 * LK * 2 > (size_t)64 * LCB * 4)
                             ? (size_t)64 * LK * 2 : (size_t)64 * LCB * 4;
    __shared__ alignas(16) char smem[SMB];
    _Float16* xs  = (_Float16*)smem;
    float*   cbuf = (float*)smem;
    __shared__ float cs_sh[STATS ? CB : 1];
    __shared__ float cq_sh[STATS ? CB : 1];

    const int rb = blockIdx.x / NCB;
    const int cblk = blockIdx.x - rb * NCB;
    const int row0 = rb * 64;
    const int colB = cblk * CB;
    const int t = threadIdx.x;

    if (STATS) {
        for (int c = t; c < CB; c += 256) { cs_sh[c] = 0.f; cq_sh[c] = 0.f; }
    }

    // ---- stage x rows (optionally BN+lrelu fused) into LDS fp16 ----
    if constexpr (__is_same(InT, _Float16)) {
        for (int i = t * 8; i < 64 * K; i += 256 * 8) {
            int r = i / K, c = i - (i / K) * K;
            half8_t v = {};
            if (row0 + r < n) v = *(const half8_t*)&x[(size_t)(row0 + r) * K + c];
            if (scale) {
#pragma unroll
                for (int j = 0; j < 8; ++j) {
                    float f = (float)v[j] * scale[c + j] + shift[c + j];
                    v[j] = (_Float16)(f > 0.f ? f : ACT_SLOPE * f);
                }
            }
            *(half8_t*)&xs[r * LK + c] = v;
        }
    } else {
        for (int i = t * 4; i < 64 * K; i += 256 * 4) {
            int r = i / K, c = i - (i / K) * K;
            float4 v = make_float4(0.f, 0.f, 0.f, 0.f);
            if (row0 + r < n) v = *(const float4*)&x[(size_t)(row0 + r) * K + c];
            if (scale) {
                v.x = v.x * scale[c] + shift[c];         v.x = v.x > 0.f ? v.x : ACT_SLOPE * v.x;
                v.y = v.y * scale[c + 1] + shift[c + 1]; v.y = v.y > 0.f ? v.y : ACT_SLOPE * v.y;
                v.z = v.z * scale[c + 2] + shift[c + 2]; v.z = v.z > 0.f ? v.z : ACT_SLOPE * v.z;
                v.w = v.w * scale[c + 3] + shift[c + 3]; v.w = v.w > 0.f ? v.w : ACT_SLOPE * v.w;
            }
            half4_t h4 = { (_Float16)v.x, (_Float16)v.y, (_Float16)v.z, (_Float16)v.w };
            *(half4_t*)&xs[r * LK + c] = h4;
        }
    }
    __syncthreads();

    const int w = t >> 6, l = t & 63;
    const int l16 = l & 15, quad = l >> 4;
    const int lc0 = (w % NW_C) * 64;          // block-local col base of this wave
    const int gc0 = colB + lc0;               // global col base
    const int mbase = (w / NW_C) * (16 * NW_C);
    // fragment-major base for this wave's col-block, lane-contiguous
    const _Float16* wtw = wt + (size_t)(gc0 >> 6) * KS * 4 * 512 + l * 8;

    f32x4 acc[RT][4] = {};
    half8_t bA[4], bB[4];
    auto loadB = [&](int k0, half8_t* bf) {
        const _Float16* p = wtw + (size_t)(k0 >> 5) * 4 * 512;
#pragma unroll
        for (int tt = 0; tt < 4; ++tt)
            bf[tt] = *(const half8_t*)&p[tt * 512];
    };
    auto doMM = [&](int k0, half8_t* bf) {
        half8_t a[RT];
#pragma unroll
        for (int rt = 0; rt < RT; ++rt)
            a[rt] = *(const half8_t*)&xs[(mbase + rt * 16 + l16) * LK + k0 + quad * 8];
#pragma unroll
        for (int rt = 0; rt < RT; ++rt)
#pragma unroll
            for (int tt = 0; tt < 4; ++tt)
                acc[rt][tt] = __builtin_amdgcn_mfma_f32_16x16x32_f16(a[rt], bf[tt],
                                                                     acc[rt][tt], 0, 0, 0);
    };
    loadB(0, bA);
#pragma unroll
    for (int k0 = 0; k0 < K; k0 += 64) {
        loadB(k0 + 32, bB);
        doMM(k0, bA);
        if (k0 + 64 < K) loadB(k0 + 64, bA);
        doMM(k0 + 32, bB);
    }

    // ---- epilogue: acc -> cbuf (+bias), stats from registers ----
    __syncthreads();   // xs dead (a-frags consumed), cbuf takes over smem
#pragma unroll
    for (int rt = 0; rt < RT; ++rt) {
#pragma unroll
        for (int tt = 0; tt < 4; ++tt) {
            int lcol = lc0 + tt * 16 + l16;
            float bb = bias ? bias[colB + lcol] : 0.f;
            float s = 0.f, q = 0.f;
#pragma unroll
            for (int i = 0; i < 4; ++i) {
                int lrow = mbase + rt * 16 + quad * 4 + i;
                float v = acc[rt][tt][i] + bb;
                cbuf[lrow * LCB + lcol] = v;
                if (STATS && row0 + lrow < n) { s += v; q += v * v; }
            }
            if constexpr (STATS) {
                s += __shfl_xor(s, 16, 64); s += __shfl_xor(s, 32, 64);
                q += __shfl_xor(q, 16, 64); q += __shfl_xor(q, 32, 64);
                if (quad == 0) {
                    atomicAdd(&cs_sh[lcol], s);
                    atomicAdd(&cq_sh[lcol], q);
                }
            }
        }
    }
    __syncthreads();
    if constexpr (STATS) {
        for (int c = t; c < CB; c += 256)
            pbn[(size_t)rb * C + colB + c] = make_float2(cs_sh[c], cq_sh[c]);
    }
    // ---- coalesced row-major store ----
    for (int i = t * 4; i < 64 * CB; i += 256 * 4) {
        int r = i / CB, c = i - (i / CB) * CB;
        if (row0 + r < n) {
            float4 v4 = *(const float4*)&cbuf[r * LCB + c];
            if constexpr (__is_same(OutT, float)) {
                *(float4*)&out[(size_t)(row0 + r) * C + colB + c] = v4;
            } else {
                half4_t h4 = { (_Float16)v4.x, (_Float16)v4.y,
                               (_Float16)v4.z, (_Float16)v4.w };
                *(half4_t*)&out[(size_t)(row0 + r) * C + colB + c] = h4;
            }
        }
    }
}

// ---- fused softmax + weighted gather over the GEMM *input* rows ----
template<int C>
__global__ __launch_bounds__(256) void
attn_aggregate(const _Float16* __restrict__ h, const int* __restrict__ srcs,
               const int* __restrict__ ptr, const float* __restrict__ e_n,
               const float* __restrict__ f_n, _Float16* __restrict__ out) {
    constexpr int RL = C / 8;          // lanes per row: 8 (C=64) or 16 (C=128)
    constexpr int G  = 64 / RL;        // row groups per wave: 8 or 4
    int d = blockIdx.x * 4 + (threadIdx.x >> 6);
    if (d >= N_NODES) return;
    int l  = threadIdx.x & 63;
    int b0 = ptr[d], b1 = ptr[d + 1];
    int deg = b1 - b0;
    float fd = f_n[d];
    const int g  = l / RL;
    const int cl = l % RL;
    float acc[8] = {0.f, 0.f, 0.f, 0.f, 0.f, 0.f, 0.f, 0.f};

    if (deg <= 64) {
        int sj = 0; float lg = -1e30f;
        if (l < deg) {
            sj = srcs[b0 + l];
            float v = e_n[sj] + fd;
            lg = v > 0.f ? v : GAT_SLOPE * v;
        }
        float m  = wred_max(lg);
        float e0 = (l < deg) ? __expf(lg - m) : 0.f;
        float ex = e0 / wred_sum(e0);

        int jj = 0;
        for (; jj + 4 * G <= deg; jj += 4 * G) {     // 4 loads in flight / group
            float wk[4]; int sk[4];
#pragma unroll
            for (int k = 0; k < 4; ++k) {
                int j = jj + k * G + g;
                wk[k] = __shfl(ex, j, 64);
                sk[k] = __shfl(sj, j, 64);
            }
            half8_t v[4];
#pragma unroll
            for (int k = 0; k < 4; ++k)
                v[k] = *(const half8_t*)&h[(size_t)sk[k] * C + cl * 8];
#pragma unroll
            for (int k = 0; k < 4; ++k)
#pragma unroll
                for (int i = 0; i < 8; ++i)
                    acc[i] += wk[k] * (float)v[k][i];
        }
        for (; jj + 2 * G <= deg; jj += 2 * G) {
            float w1 = __shfl(ex, jj + g, 64);
            int   s1 = __shfl(sj, jj + g, 64);
            float w2 = __shfl(ex, jj + G + g, 64);
            int   s2 = __shfl(sj, jj + G + g, 64);
            half8_t v1 = *(const half8_t*)&h[(size_t)s1 * C + cl * 8];
            half8_t v2 = *(const half8_t*)&h[(size_t)s2 * C + cl * 8];
#pragma unroll
            for (int i = 0; i < 8; ++i)
                acc[i] += w1 * (float)v1[i] + w2 * (float)v2[i];
        }
        for (; jj < deg; jj += G) {                  // exact tail
            int j = jj + g;
            float wk = __shfl(ex, j, 64);
            int   sk = __shfl(sj, j, 64);
            if (j < deg) {
                half8_t v = *(const half8_t*)&h[(size_t)sk * C + cl * 8];
#pragma unroll
                for (int i = 0; i < 8; ++i) acc[i] += wk * (float)v[i];
            }
        }
    } else {
        float m_l = -1e30f, den_l = 0.f;
        for (int j = b0 + l; j < b1; j += 64) {
            float lg = e_n[srcs[j]] + fd;
            lg = lg > 0.f ? lg : GAT_SLOPE * lg;
            float nm = fmaxf(m_l, lg);
            den_l = den_l * __expf(m_l - nm) + __expf(lg - nm);
            m_l = nm;
        }
        float m = wred_max(m_l);
        float inv = 1.f / wred_sum(den_l * __expf(m_l - m));
        for (int c0 = b0; c0 < b1; c0 += 64) {
            int jl = c0 + l;
            int sj = 0; float ex = 0.f;
            if (jl < b1) {
                sj = srcs[jl];
                float lg = e_n[sj] + fd;
                lg = lg > 0.f ? lg : GAT_SLOPE * lg;
                ex = __expf(lg - m) * inv;
            }
            int nE = min(64, b1 - c0);
            for (int jj = 0; jj < nE; jj += 2 * G) {
                int j1 = jj + g, j2 = jj + G + g;
                float w1 = __shfl(ex, j1, 64);
                int   s1 = __shfl(sj, j1, 64);
                float w2 = __shfl(ex, j2, 64);
                int   s2 = __shfl(sj, j2, 64);
                half8_t v1 = *(const half8_t*)&h[(size_t)s1 * C + cl * 8];
                half8_t v2 = *(const half8_t*)&h[(size_t)s2 * C + cl * 8];
#pragma unroll
                for (int i = 0; i < 8; ++i)
                    acc[i] += w1 * (float)v1[i] + w2 * (float)v2[i];
            }
        }
    }
#pragma unroll
    for (int mm = RL; mm < 64; mm <<= 1)
#pragma unroll
        for (int i = 0; i < 8; ++i) acc[i] += __shfl_xor(acc[i], mm, 64);
    if (g == 0) {
        int c = cl * 8;
        half8_t o;
#pragma unroll
        for (int i = 0; i < 8; ++i) o[i] = (_Float16)acc[i];
        *(half8_t*)&out[(size_t)d * C + c] = o;
    }
}

// reduce per-GEMM-rowblock partials -> per-column scale/shift; wave per column
template<int C, int PB>
__global__ __launch_bounds__(256) void
bn_coef(const float2* __restrict__ partial, const float* __restrict__ gamma,
        const float* __restrict__ beta, float* __restrict__ scale,
        float* __restrict__ shift) {
    int w = threadIdx.x >> 6, l = threadIdx.x & 63;
    int c = blockIdx.x * 4 + w;
    float s = 0.f, q = 0.f;
    for (int b = l; b < PB; b += 64) {
        float2 p = partial[(size_t)b * C + c];
        s += p.x; q += p.y;
    }
    s = wred_sum(s); q = wred_sum(q);
    if (l == 0) {
        float mu  = s / N_NODES;
        float var = q / N_NODES - mu * mu;
        float sc = gamma[c] * rsqrtf(var + EPS_BN);
        scale[c] = sc;
        shift[c] = beta[c] - mu * sc;
    }
}

extern "C" void kernel_launch(void* const* d_in, const int* in_sizes, int n_in,
                              void* d_out, int out_size, void* d_ws, size_t ws_size,
                              hipStream_t stream) {
    const float* emb  = (const float*)d_in[0];
    const int*   ei   = (const int*)  d_in[1];
    const float* W1   = (const float*)d_in[2];
    const float* as1  = (const float*)d_in[3];
    const float* ad1  = (const float*)d_in[4];
    const float* b1   = (const float*)d_in[5];
    const float* g1   = (const float*)d_in[6];
    const float* be1  = (const float*)d_in[7];
    const float* W2   = (const float*)d_in[8];
    const float* as2  = (const float*)d_in[9];
    const float* ad2  = (const float*)d_in[10];
    const float* b2   = (const float*)d_in[11];
    const float* g2   = (const float*)d_in[12];
    const float* be2  = (const float*)d_in[13];
    const float* Wf   = (const float*)d_in[14];
    const float* bf   = (const float*)d_in[15];
    float* out = (float*)d_out;

    char* w = (char*)d_ws;
    auto alloc = [&](size_t bytes) {
        char* p = w;
        w += (bytes + 255) & ~(size_t)255;
        return (void*)p;
    };
    // embh and agg1 are contiguous (each 6.4MB, 256B-aligned) — together they
    // are reused as z1h (12.8MB) after both are dead.
    _Float16* embh = (_Float16*)alloc((size_t)N_NODES * 64 * 2);   // emb fp16
    _Float16* agg1 = (_Float16*)alloc((size_t)N_NODES * 64 * 2);   // layer-1 aggregate
    _Float16* out1 = (_Float16*)alloc((size_t)N_NODES * 128 * 2);  // agg1 @ W1 + b1
    _Float16* agg2 = (_Float16*)alloc((size_t)N_NODES * 128 * 2);  // layer-2 aggregate
    _Float16* out2 = (_Float16*)alloc((size_t)N_NODES * 256 * 2);  // agg2 @ W2 + b2
    _Float16* z1h  = embh;                       // alias: lrelu(bn(out1)), 12.8MB
    unsigned* bedge = (unsigned*)out2;           // alias: bucket edges (4MB), dead
                                                 // before out2 is written
    float*  e_n  = (float*) alloc((size_t)N_NODES * 4);
    float*  f_n  = (float*) alloc((size_t)N_NODES * 4);
    int*    srcs = (int*)   alloc((size_t)N_TOT * 4);
    int*    bcnt = (int*)   alloc((size_t)NBUCK * 4);
    int*    ptr  = (int*)   alloc((size_t)(N_NODES + 1) * 4);
    float2* pbn  = (float2*)alloc((size_t)GB64 * 256 * 8);   // 1.6 MiB
    float*  sc1  = (float*) alloc(128 * 4);
    float*  sh1  = (float*) alloc(128 * 4);
    float*  sc2  = (float*) alloc(256 * 4);
    float*  sh2  = (float*) alloc(256 * 4);
    float*  va1  = (float*) alloc(64 * 4);
    float*  vb1  = (float*) alloc(64 * 4);
    float*  va2  = (float*) alloc(128 * 4);
    float*  vb2  = (float*) alloc(128 * 4);
    _Float16* wt1 = (_Float16*)alloc((size_t)64 * 128 * 2);
    _Float16* wt2 = (_Float16*)alloc((size_t)128 * 256 * 2);
    _Float16* wtf = (_Float16*)alloc((size_t)256 * 256 * 2);

    const int RW4 = (N_NODES + 3) / 4;   // wave-per-row grids

    // 1) init: weight fragment-major + a-vec matvecs + bcnt zero
    init_misc<<<(106496 + 384 + 255) / 256, 256, 0, stream>>>(
        W1, W2, Wf, wt1, wt2, wtf, bcnt,
        as1, ad1, as2, ad2, va1, vb1, va2, vb2);

    // 2) fused: bucket append (single-pass) ∥ emb cast + layer-1 logits
    append_emb<<<K1_NB + RW4, 256, 0, stream>>>(
        ei, bcnt, bedge, emb, va1, vb1, embh, e_n, f_n);

    // 3) per-bucket CSR
    bucket_csr<<<NBUCK, 256, 0, stream>>>(bcnt, bedge, ptr, srcs);

    // 4) layer-1 aggregate (128B rows)
    attn_aggregate<64><<<RW4, 256, 0, stream>>>(embh, srcs, ptr, e_n, f_n, agg1);

    // 5) GEMM 64->128 (+BN1 stats)
    gemm_mfma<64, 128, 128, _Float16, _Float16, true><<<GB64, 256, 0, stream>>>(
        agg1, wt1, b1, out1, N_NODES, nullptr, nullptr, pbn);
    // 6) BN1 coef (kernel boundary = the cheap cross-XCD fence)
    bn_coef<128, GB64><<<128 / 4, 256, 0, stream>>>(pbn, g1, be1, sc1, sh1);

    // 7) z1 = lrelu(bn(out1)) stored once + layer-2 logits
    ef_dots<<<RW4, 256, 0, stream>>>(out1, sc1, sh1, va2, vb2, z1h, e_n, f_n);

    // 8) layer-2 aggregate (256B rows)
    attn_aggregate<128><<<RW4, 256, 0, stream>>>(z1h, srcs, ptr, e_n, f_n, agg2);

    // 9) GEMM 128->256 (+BN2 stats)
    gemm_mfma<128, 256, 128, _Float16, _Float16, true><<<GB64 * 2, 256, 0, stream>>>(
        agg2, wt2, b2, out2, N_NODES, nullptr, nullptr, pbn);
    // 10) BN2 coef
    bn_coef<256, GB64><<<256 / 4, 256, 0, stream>>>(pbn, g2, be2, sc2, sh2);

    // 11) final linear 256->256 (BN2+lrelu fused into staging)
    gemm_mfma<256, 256, 128, _Float16, float, false><<<GB64 * 2, 256, 0, stream>>>(
        out2, wtf, bf, out, N_NODES, sc2, sh2, nullptr);
}